// Round 7
// baseline (34412.424 us; speedup 1.0000x reference)
//
#include <hip/hip_runtime.h>

// ---------------- problem constants ----------------
constexpr int N  = 325;
constexpr int B  = 64;
constexpr int T  = 12;
constexpr int HZ = 12;
constexpr int U  = 64;
constexpr int BN = B * N;     // 20800
constexpr int FC = 16;        // feature chunk per diffusion unit
constexpr int ELLW = 352;
constexpr int GRID = 512;     // <= 2 blocks/CU guaranteed co-resident
constexpr int BLK  = 256;

typedef __attribute__((ext_vector_type(8))) short short8;
typedef __attribute__((ext_vector_type(4))) float floatx4;

struct MegaArgs {
    const float* inputs; const float* S;
    const float* Wg[4]; const float* bg[4]; const float* Wc[4]; const float* bc[4];
    const float* pW; const float* pb; float* out;
    float* h0; float* h1; float* dec_in; float* ru;
    unsigned* zcat; float2* ellcv; int* nnz;
    short8* Wgh[4]; short8* Wgl[4]; short8* Wch[4]; short8* Wcl[4];
    unsigned* bar;   // [0]=count, [1]=generation
};

__device__ inline unsigned short f2bf(float f) {
    unsigned u = __float_as_uint(f);
    u += 0x7fff + ((u >> 16) & 1);
    return (unsigned short)(u >> 16);
}
__device__ inline unsigned pack_hilo(float v) {
    const unsigned short hi = f2bf(v);
    const float hif = __uint_as_float(((unsigned)hi) << 16);
    const unsigned short lo = f2bf(v - hif);
    return (unsigned)hi | ((unsigned)lo << 16);
}

// sense-reversing software grid barrier (device/agent scope)
__device__ __forceinline__ void gridsync(unsigned* bar) {
    __syncthreads();
    if (threadIdx.x == 0) {
        __threadfence();   // publish this block's writes
        const unsigned g =
            __hip_atomic_load(bar + 1, __ATOMIC_RELAXED, __HIP_MEMORY_SCOPE_AGENT);
        const unsigned prev =
            __hip_atomic_fetch_add(bar, 1u, __ATOMIC_ACQ_REL, __HIP_MEMORY_SCOPE_AGENT);
        if (prev == GRID - 1) {
            __hip_atomic_store(bar, 0u, __ATOMIC_RELAXED, __HIP_MEMORY_SCOPE_AGENT);
            __hip_atomic_store(bar + 1, g + 1u, __ATOMIC_RELEASE, __HIP_MEMORY_SCOPE_AGENT);
        } else {
            unsigned cur;
            do {
                __builtin_amdgcn_s_sleep(2);
                cur = __hip_atomic_load(bar + 1, __ATOMIC_ACQUIRE, __HIP_MEMORY_SCOPE_AGENT);
            } while (cur == g);
        }
        __threadfence();   // acquire side: see other blocks' writes
    }
    __syncthreads();
}

__global__ void init_bar(unsigned* bar) {
    if (threadIdx.x < 2) bar[threadIdx.x] = 0u;
}

// ---------------- stage device functions (grid-stride unit loops) ----------------

__device__ void st_zero(const MegaArgs& a) {
    const int n = 2 * BN * U + BN;          // h0 | h1 | dec_in contiguous
    for (int i = blockIdx.x * BLK + threadIdx.x; i < n; i += GRID * BLK)
        a.h0[i] = 0.f;
}

__device__ void st_ell(const MegaArgs& a) {
    const int w    = blockIdx.x * 4 + (threadIdx.x >> 6);
    const int lane = threadIdx.x & 63;
    for (int m = w; m < N; m += GRID * 4) {
        const float* row = a.S + m * N;
        int count = 0;
        for (int base = 0; base < N; base += 64) {
            const int nn = base + lane;
            const float v = (nn < N) ? row[nn] : 0.f;
            const unsigned long long mask = __ballot(v != 0.f);
            const int pre = __popcll(mask & ((1ull << lane) - 1ull));
            if (v != 0.f)
                a.ellcv[(count + pre) * N + m] = make_float2(v, __int_as_float(nn));
            count += __popcll(mask);
        }
        if (lane == 0) a.nnz[m] = count;
    }
}

__device__ void st_prepack(const MegaArgs& a) {
    const int w    = blockIdx.x * 4 + (threadIdx.x >> 6);
    const int lane = threadIdx.x & 63;
    const int quad = lane >> 4, l15 = lane & 15;
    const int KCs[4] = {7, 12, 7, 12};
    const int K3v[4] = {198, 384, 195, 384};
    for (int u = w; u < 456; u += GRID * 4) {
        int r = u, l = 0;
        while (r >= KCs[l] * 12) { r -= KCs[l] * 12; ++l; }
        const int gate_cnt = KCs[l] * 8;
        const bool isg = r < gate_cnt;
        const int NT = isg ? 8 : 4, Nout = isg ? 128 : 64;
        const int rr = isg ? r : r - gate_cnt;
        const int kc = rr / NT, n = rr % NT;
        const float* W = isg ? a.Wg[l] : a.Wc[l];
        short8* Wh = isg ? a.Wgh[l] : a.Wch[l];
        short8* Wl = isg ? a.Wgl[l] : a.Wcl[l];
        const int K3 = K3v[l];
        short8 hv, lv;
        #pragma unroll
        for (int j = 0; j < 8; ++j) {
            const int k   = kc * 32 + quad * 8 + j;
            const int col = n * 16 + l15;
            const float wv = (k < K3) ? W[k * Nout + col] : 0.f;
            const unsigned short h = f2bf(wv);
            const float hf = __uint_as_float(((unsigned)h) << 16);
            hv[j] = (short)h;
            lv[j] = (short)f2bf(wv - hf);
        }
        const size_t off = (size_t)(kc * NT + n) * 64 + lane;
        Wh[off] = hv;
        Wl[off] = lv;
    }
}

// sparse Chebyshev diffusion; unit = (chunk, batch); writes packed zcat
__device__ void st_diff(const MegaArgs& a, bool rmul, const float* __restrict__ x,
                        const float* __restrict__ h, int din, int F, int K3p,
                        float* __restrict__ s0, float* __restrict__ s1)
{
    const int tid = threadIdx.x;
    const int nchunks = (F + FC - 1) / FC;
    const int units = nchunks * B;
    for (int u = blockIdx.x; u < units; u += GRID) {
        const int b   = u & 63;
        const int fc0 = (u >> 6) * FC;

        for (int idx = tid; idx < N * FC; idx += BLK) {
            const int n  = idx / FC;
            const int f  = idx - n * FC;
            const int gf = fc0 + f;
            float v = 0.f;
            if (gf < F) {
                const int row = b * N + n;
                v = (gf < din) ? x[row * din + gf]
                               : h[row * U + (gf - din)];
                if (rmul && gf >= din) v *= a.ru[row * 128 + (gf - din)];
                a.zcat[(size_t)row * K3p + gf] = pack_hilo(v);
            }
            s0[idx] = v;
        }
        if (fc0 == 0) {   // zero K-padding strip [3F, K3p)
            const int pad = K3p - 3 * F;
            for (int idx = tid; idx < N * pad; idx += BLK) {
                const int n = idx / pad;
                const int c = idx - n * pad;
                a.zcat[(size_t)(b * N + n) * K3p + 3 * F + c] = 0u;
            }
        }
        __syncthreads();

        const int fg = (tid & 3) * 4;
        const int mi = tid >> 2;

        for (int pass = 0; pass < 6; ++pass) {
            const int m = pass * 64 + mi;
            if (m < N) {
                const int cnt = a.nnz[m];
                float a0 = 0.f, a1 = 0.f, a2 = 0.f, a3 = 0.f;
                #pragma unroll 4
                for (int j = 0; j < cnt; ++j) {
                    const float2 cv = a.ellcv[j * N + m];
                    const int col = __float_as_int(cv.y);
                    const float4 v = *(const float4*)&s0[col * FC + fg];
                    a0 += cv.x * v.x; a1 += cv.x * v.y; a2 += cv.x * v.z; a3 += cv.x * v.w;
                }
                *(float4*)&s1[m * FC + fg] = make_float4(a0, a1, a2, a3);
                const int row = b * N + m;
                const float vals[4] = {a0, a1, a2, a3};
                #pragma unroll
                for (int j = 0; j < 4; ++j) {
                    const int gf = fc0 + fg + j;
                    if (gf < F) a.zcat[(size_t)row * K3p + F + gf] = pack_hilo(vals[j]);
                }
            }
        }
        __syncthreads();

        for (int pass = 0; pass < 6; ++pass) {
            const int m = pass * 64 + mi;
            if (m < N) {
                const int cnt = a.nnz[m];
                float a0 = 0.f, a1 = 0.f, a2 = 0.f, a3 = 0.f;
                #pragma unroll 4
                for (int j = 0; j < cnt; ++j) {
                    const float2 cv = a.ellcv[j * N + m];
                    const int col = __float_as_int(cv.y);
                    const float4 v = *(const float4*)&s1[col * FC + fg];
                    a0 += cv.x * v.x; a1 += cv.x * v.y; a2 += cv.x * v.z; a3 += cv.x * v.w;
                }
                const int row = b * N + m;
                const float vals[4] = {a0, a1, a2, a3};
                #pragma unroll
                for (int j = 0; j < 4; ++j) {
                    const int gf = fc0 + fg + j;
                    if (gf < F)
                        a.zcat[(size_t)row * K3p + 2 * F + gf] =
                            pack_hilo(2.f * vals[j] - s0[m * FC + fg + j]);
                }
            }
        }
        __syncthreads();
    }
}

// ru = sigmoid(zcat @ Wg + bg); unit = 64-row tile (325 units)
__device__ void st_gate(const MegaArgs& a, int l, int K3p) {
    const int tid = threadIdx.x, wave = tid >> 6, lane = tid & 63;
    const int quad = lane >> 4, l15 = lane & 15;
    const short8* __restrict__ Wh = a.Wgh[l];
    const short8* __restrict__ Wl = a.Wgl[l];
    const float*  __restrict__ bias = a.bg[l];
    const int KC = K3p >> 5;
    for (int u = blockIdx.x; u < BN / 64; u += GRID) {
        const int row0 = u * 64 + wave * 16;
        floatx4 acc[8];
        #pragma unroll
        for (int n = 0; n < 8; ++n) {
            const float bv = bias[n * 16 + l15];
            acc[n] = (floatx4){bv, bv, bv, bv};
        }
        const unsigned* __restrict__ zrow =
            a.zcat + (size_t)(row0 + l15) * K3p + quad * 8;
        for (int kc = 0; kc < KC; ++kc) {
            const uint4* p = (const uint4*)(zrow + kc * 32);
            const uint4 u0 = p[0], u1 = p[1];
            const unsigned uu[8] = {u0.x, u0.y, u0.z, u0.w, u1.x, u1.y, u1.z, u1.w};
            short8 ahi, alo;
            #pragma unroll
            for (int j = 0; j < 8; ++j) {
                ahi[j] = (short)(uu[j] & 0xffffu);
                alo[j] = (short)(uu[j] >> 16);
            }
            const short8* wh = Wh + (size_t)(kc * 8) * 64 + lane;
            const short8* wl = Wl + (size_t)(kc * 8) * 64 + lane;
            #pragma unroll
            for (int n = 0; n < 8; ++n) {
                const short8 bh = wh[n * 64], bl = wl[n * 64];
                acc[n] = __builtin_amdgcn_mfma_f32_16x16x32_bf16(ahi, bh, acc[n], 0, 0, 0);
                acc[n] = __builtin_amdgcn_mfma_f32_16x16x32_bf16(ahi, bl, acc[n], 0, 0, 0);
                acc[n] = __builtin_amdgcn_mfma_f32_16x16x32_bf16(alo, bh, acc[n], 0, 0, 0);
            }
        }
        #pragma unroll
        for (int n = 0; n < 8; ++n) {
            const int col = n * 16 + l15;
            #pragma unroll
            for (int r = 0; r < 4; ++r) {
                const int row = row0 + quad * 4 + r;
                a.ru[(size_t)row * 128 + col] = 1.f / (1.f + __expf(-acc[n][r]));
            }
        }
    }
}

// c = tanh(zcat @ Wc + bc); h = u*h + (1-u)*c; optional fused projection
__device__ void st_cand(const MegaArgs& a, int l, int K3p, float* __restrict__ h,
                        bool doproj, float* __restrict__ outp)
{
    const int tid = threadIdx.x, wave = tid >> 6, lane = tid & 63;
    const int quad = lane >> 4, l15 = lane & 15;
    const short8* __restrict__ Wh = a.Wch[l];
    const short8* __restrict__ Wl = a.Wcl[l];
    const float*  __restrict__ bias = a.bc[l];
    const int KC = K3p >> 5;
    for (int u = blockIdx.x; u < BN / 64; u += GRID) {
        const int row0 = u * 64 + wave * 16;
        floatx4 acc[4];
        #pragma unroll
        for (int n = 0; n < 4; ++n) {
            const float bv = bias[n * 16 + l15];
            acc[n] = (floatx4){bv, bv, bv, bv};
        }
        const unsigned* __restrict__ zrow =
            a.zcat + (size_t)(row0 + l15) * K3p + quad * 8;
        for (int kc = 0; kc < KC; ++kc) {
            const uint4* p = (const uint4*)(zrow + kc * 32);
            const uint4 u0 = p[0], u1 = p[1];
            const unsigned uu[8] = {u0.x, u0.y, u0.z, u0.w, u1.x, u1.y, u1.z, u1.w};
            short8 ahi, alo;
            #pragma unroll
            for (int j = 0; j < 8; ++j) {
                ahi[j] = (short)(uu[j] & 0xffffu);
                alo[j] = (short)(uu[j] >> 16);
            }
            const short8* wh = Wh + (size_t)(kc * 4) * 64 + lane;
            const short8* wl = Wl + (size_t)(kc * 4) * 64 + lane;
            #pragma unroll
            for (int n = 0; n < 4; ++n) {
                const short8 bh = wh[n * 64], bl = wl[n * 64];
                acc[n] = __builtin_amdgcn_mfma_f32_16x16x32_bf16(ahi, bh, acc[n], 0, 0, 0);
                acc[n] = __builtin_amdgcn_mfma_f32_16x16x32_bf16(ahi, bl, acc[n], 0, 0, 0);
                acc[n] = __builtin_amdgcn_mfma_f32_16x16x32_bf16(alo, bh, acc[n], 0, 0, 0);
            }
        }
        float hn[4][4];
        #pragma unroll
        for (int n = 0; n < 4; ++n) {
            const int col = n * 16 + l15;
            #pragma unroll
            for (int r = 0; r < 4; ++r) {
                const int row = row0 + quad * 4 + r;
                const float c  = tanhf(acc[n][r]);
                const float ug = a.ru[(size_t)row * 128 + 64 + col];
                const float hv = h[(size_t)row * 64 + col];
                const float nh = ug * hv + (1.f - ug) * c;
                h[(size_t)row * 64 + col] = nh;
                hn[n][r] = nh;
            }
        }
        if (doproj) {
            float partial[4] = {0.f, 0.f, 0.f, 0.f};
            #pragma unroll
            for (int n = 0; n < 4; ++n) {
                const float w = a.pW[n * 16 + l15];
                #pragma unroll
                for (int r = 0; r < 4; ++r) partial[r] += hn[n][r] * w;
            }
            #pragma unroll
            for (int r = 0; r < 4; ++r) {
                float v = partial[r];
                v += __shfl_xor(v, 1, 16);
                v += __shfl_xor(v, 2, 16);
                v += __shfl_xor(v, 4, 16);
                v += __shfl_xor(v, 8, 16);
                if (l15 == 0) {
                    const int row = row0 + quad * 4 + r;
                    const float o = v + a.pb[0];
                    outp[row]     = o;
                    a.dec_in[row] = o;
                }
            }
        }
    }
}

// ---------------- the persistent mega-kernel (software grid barrier) ----------------

__global__ __launch_bounds__(BLK, 2)
void megakernel(MegaArgs a)
{
    __shared__ __align__(16) float s0[N * FC];
    __shared__ __align__(16) float s1[N * FC];

    st_zero(a);
    st_ell(a);
    st_prepack(a);
    gridsync(a.bar);

    auto cell = [&](const float* x, int din, int F, int K3p, float* h, int l,
                    bool proj, float* outp) {
        st_diff(a, false, x, h, din, F, K3p, s0, s1);  gridsync(a.bar);
        st_gate(a, l, K3p);                            gridsync(a.bar);
        st_diff(a, true, x, h, din, F, K3p, s0, s1);   gridsync(a.bar);
        st_cand(a, l, K3p, h, proj, outp);             gridsync(a.bar);
    };

    for (int t = 0; t < T; ++t) {
        cell(a.inputs + (size_t)t * BN * 2, 2, 66, 224, a.h0, 0, false, nullptr);
        cell(a.h0, 64, 128, 384, a.h1, 1, false, nullptr);
    }
    for (int s = 0; s < HZ; ++s) {
        cell(a.dec_in, 1, 65, 224, a.h0, 2, false, nullptr);
        cell(a.h0, 64, 128, 384, a.h1, 3, true, a.out + (size_t)s * BN);
    }
}

// ---------------- host launcher ----------------

extern "C" void kernel_launch(void* const* d_in, const int* in_sizes, int n_in,
                              void* d_out, int out_size, void* d_ws, size_t ws_size,
                              hipStream_t stream)
{
    MegaArgs a;
    a.inputs = (const float*)d_in[0];
    a.S      = (const float*)d_in[1];
    for (int l = 0; l < 4; ++l) {
        a.Wg[l] = (const float*)d_in[2 + l * 4 + 0];
        a.bg[l] = (const float*)d_in[2 + l * 4 + 1];
        a.Wc[l] = (const float*)d_in[2 + l * 4 + 2];
        a.bc[l] = (const float*)d_in[2 + l * 4 + 3];
    }
    a.pW  = (const float*)d_in[18];
    a.pb  = (const float*)d_in[19];
    a.out = (float*)d_out;

    float* ws = (float*)d_ws;
    a.h0     = ws;
    a.h1     = a.h0 + BN * U;
    a.dec_in = a.h1 + BN * U;
    a.ru     = a.dec_in + BN;
    a.zcat   = (unsigned*)(a.ru + BN * 128);
    a.ellcv  = (float2*)(a.zcat + (size_t)BN * 384);
    a.nnz    = (int*)(a.ellcv + (size_t)ELLW * N);
    char* wp = (char*)(a.nnz + ((N + 3) & ~3));
    wp = (char*)(((uintptr_t)wp + 63) & ~(uintptr_t)63);

    const int K3ps[4] = {224, 384, 224, 384};
    size_t off = 0;
    for (int l = 0; l < 4; ++l) {
        const size_t ge = (size_t)K3ps[l] * 128, ce = (size_t)K3ps[l] * 64;
        a.Wgh[l] = (short8*)(wp + off); off += ge * 2;
        a.Wgl[l] = (short8*)(wp + off); off += ge * 2;
        a.Wch[l] = (short8*)(wp + off); off += ce * 2;
        a.Wcl[l] = (short8*)(wp + off); off += ce * 2;
    }
    off = (off + 63) & ~(size_t)63;
    a.bar = (unsigned*)(wp + off);

    init_bar<<<1, 64, 0, stream>>>(a.bar);
    megakernel<<<GRID, BLK, 0, stream>>>(a);
}

// Round 9
// 13512.082 us; speedup vs baseline: 2.5468x; 2.5468x over previous
//
#include <hip/hip_runtime.h>

// ---------------- problem constants ----------------
constexpr int N  = 325;
constexpr int B  = 64;
constexpr int T  = 12;
constexpr int HZ = 12;
constexpr int U  = 64;
constexpr int BN = B * N;     // 20800
constexpr int FC = 16;        // feature chunk width in diffusion
constexpr int ELLW = 352;
constexpr int SGRID = 512;    // setup kernel grid
constexpr int MBLK  = 1024;   // per-sample block = 16 waves
constexpr int NTILE = (N + 15) / 16;  // 21 MFMA row tiles per sample

typedef __attribute__((ext_vector_type(8))) short short8;
typedef __attribute__((ext_vector_type(4))) float floatx4;

struct MegaArgs {
    const float* inputs; const float* S;
    const float* Wg[4]; const float* bg[4]; const float* Wc[4]; const float* bc[4];
    const float* pW; const float* pb; float* out;
    float* h0; float* h1; float* dec_in; float* ru;
    unsigned* zcat; float2* ellcv; int* nnz;
    short8* Wgh[4]; short8* Wgl[4]; short8* Wch[4]; short8* Wcl[4];
};

__device__ inline unsigned short f2bf(float f) {
    unsigned u = __float_as_uint(f);
    u += 0x7fff + ((u >> 16) & 1);
    return (unsigned short)(u >> 16);
}
__device__ inline unsigned pack_hilo(float v) {
    const unsigned short hi = f2bf(v);
    const float hif = __uint_as_float(((unsigned)hi) << 16);
    const unsigned short lo = f2bf(v - hif);
    return (unsigned)hi | ((unsigned)lo << 16);
}

// ---------------- setup kernel (zero states, ELL build, weight prepack) ----------------

__global__ __launch_bounds__(256)
void setup_kernel(MegaArgs a)
{
    const int nz = 2 * BN * U + BN;   // h0 | h1 | dec_in contiguous
    for (int i = blockIdx.x * 256 + threadIdx.x; i < nz; i += SGRID * 256)
        a.h0[i] = 0.f;

    const int w    = blockIdx.x * 4 + (threadIdx.x >> 6);
    const int lane = threadIdx.x & 63;

    // ELL build: one wave per row
    for (int m = w; m < N; m += SGRID * 4) {
        const float* row = a.S + m * N;
        int count = 0;
        for (int base = 0; base < N; base += 64) {
            const int nn = base + lane;
            const float v = (nn < N) ? row[nn] : 0.f;
            const unsigned long long mask = __ballot(v != 0.f);
            const int pre = __popcll(mask & ((1ull << lane) - 1ull));
            if (v != 0.f)
                a.ellcv[(count + pre) * N + m] = make_float2(v, __int_as_float(nn));
            count += __popcll(mask);
        }
        if (lane == 0) a.nnz[m] = count;
    }

    // weight prepack into MFMA B-fragment order, split bf16 hi/lo
    const int quad = lane >> 4, l15 = lane & 15;
    const int KCs[4] = {7, 12, 7, 12};
    const int K3v[4] = {198, 384, 195, 384};
    for (int u = w; u < 456; u += SGRID * 4) {
        int r = u, l = 0;
        while (r >= KCs[l] * 12) { r -= KCs[l] * 12; ++l; }
        const int gate_cnt = KCs[l] * 8;
        const bool isg = r < gate_cnt;
        const int NT = isg ? 8 : 4, Nout = isg ? 128 : 64;
        const int rr = isg ? r : r - gate_cnt;
        const int kc = rr / NT, n = rr % NT;
        const float* W = isg ? a.Wg[l] : a.Wc[l];
        short8* Wh = isg ? a.Wgh[l] : a.Wch[l];
        short8* Wl = isg ? a.Wgl[l] : a.Wcl[l];
        const int K3 = K3v[l];
        short8 hv, lv;
        #pragma unroll
        for (int j = 0; j < 8; ++j) {
            const int k   = kc * 32 + quad * 8 + j;
            const int col = n * 16 + l15;
            const float wv = (k < K3) ? W[k * Nout + col] : 0.f;
            const unsigned short h = f2bf(wv);
            const float hf = __uint_as_float(((unsigned)h) << 16);
            hv[j] = (short)h;
            lv[j] = (short)f2bf(wv - hf);
        }
        const size_t off = (size_t)(kc * NT + n) * 64 + lane;
        Wh[off] = hv;
        Wl[off] = lv;
    }
}

// ---------------- per-sample stage device functions (1024 threads) ----------------
// (byte-identical logic to Round 8 — under test)

__device__ void diff_b(const MegaArgs& a, bool rmul, const float* __restrict__ x,
                       const float* __restrict__ h, int din, int F, int K3p,
                       float* __restrict__ s0, float* __restrict__ s1, int b)
{
    const int tid = threadIdx.x;
    const int nchunks = (F + FC - 1) / FC;
    for (int c = 0; c < nchunks; ++c) {
        const int fc0 = c * FC;

        for (int idx = tid; idx < N * FC; idx += MBLK) {
            const int n  = idx / FC;
            const int f  = idx - n * FC;
            const int gf = fc0 + f;
            float v = 0.f;
            if (gf < F) {
                const int row = b * N + n;
                v = (gf < din) ? x[row * din + gf]
                               : h[row * U + (gf - din)];
                if (rmul && gf >= din) v *= a.ru[row * 128 + (gf - din)];
                a.zcat[(size_t)row * K3p + gf] = pack_hilo(v);
            }
            s0[idx] = v;
        }
        if (c == 0) {   // zero K-padding strip [3F, K3p)
            const int pad = K3p - 3 * F;
            for (int idx = tid; idx < N * pad; idx += MBLK) {
                const int n = idx / pad;
                const int cc = idx - n * pad;
                a.zcat[(size_t)(b * N + n) * K3p + 3 * F + cc] = 0u;
            }
        }
        __syncthreads();

        const int fg = (tid & 3) * 4;
        const int mi = tid >> 2;     // 0..255 rows in flight

        for (int pass = 0; pass < 2; ++pass) {
            const int m = pass * 256 + mi;
            if (m < N) {
                const int cnt = a.nnz[m];
                float a0 = 0.f, a1 = 0.f, a2 = 0.f, a3 = 0.f;
                #pragma unroll 4
                for (int j = 0; j < cnt; ++j) {
                    const float2 cv = a.ellcv[j * N + m];
                    const int col = __float_as_int(cv.y);
                    const float4 v = *(const float4*)&s0[col * FC + fg];
                    a0 += cv.x * v.x; a1 += cv.x * v.y; a2 += cv.x * v.z; a3 += cv.x * v.w;
                }
                *(float4*)&s1[m * FC + fg] = make_float4(a0, a1, a2, a3);
                const int row = b * N + m;
                const float vals[4] = {a0, a1, a2, a3};
                #pragma unroll
                for (int j = 0; j < 4; ++j) {
                    const int gf = fc0 + fg + j;
                    if (gf < F) a.zcat[(size_t)row * K3p + F + gf] = pack_hilo(vals[j]);
                }
            }
        }
        __syncthreads();

        for (int pass = 0; pass < 2; ++pass) {
            const int m = pass * 256 + mi;
            if (m < N) {
                const int cnt = a.nnz[m];
                float a0 = 0.f, a1 = 0.f, a2 = 0.f, a3 = 0.f;
                #pragma unroll 4
                for (int j = 0; j < cnt; ++j) {
                    const float2 cv = a.ellcv[j * N + m];
                    const int col = __float_as_int(cv.y);
                    const float4 v = *(const float4*)&s1[col * FC + fg];
                    a0 += cv.x * v.x; a1 += cv.x * v.y; a2 += cv.x * v.z; a3 += cv.x * v.w;
                }
                const int row = b * N + m;
                const float vals[4] = {a0, a1, a2, a3};
                #pragma unroll
                for (int j = 0; j < 4; ++j) {
                    const int gf = fc0 + fg + j;
                    if (gf < F)
                        a.zcat[(size_t)row * K3p + 2 * F + gf] =
                            pack_hilo(2.f * vals[j] - s0[m * FC + fg + j]);
                }
            }
        }
        __syncthreads();
    }
}

__device__ void gate_b(const MegaArgs& a, int l, int K3p, int b)
{
    const int wave = threadIdx.x >> 6, lane = threadIdx.x & 63;
    const int quad = lane >> 4, l15 = lane & 15;
    const short8* __restrict__ Wh = a.Wgh[l];
    const short8* __restrict__ Wl = a.Wgl[l];
    const float*  __restrict__ bias = a.bg[l];
    const int KC = K3p >> 5;
    for (int tile = wave; tile < NTILE; tile += 16) {
        floatx4 acc[8];
        #pragma unroll
        for (int n = 0; n < 8; ++n) {
            const float bv = bias[n * 16 + l15];
            acc[n] = (floatx4){bv, bv, bv, bv};
        }
        int nodeA = tile * 16 + l15;
        if (nodeA > N - 1) nodeA = N - 1;
        const unsigned* __restrict__ zrow =
            a.zcat + (size_t)(b * N + nodeA) * K3p + quad * 8;
        for (int kc = 0; kc < KC; ++kc) {
            const uint4* p = (const uint4*)(zrow + kc * 32);
            const uint4 u0 = p[0], u1 = p[1];
            const unsigned uu[8] = {u0.x, u0.y, u0.z, u0.w, u1.x, u1.y, u1.z, u1.w};
            short8 ahi, alo;
            #pragma unroll
            for (int j = 0; j < 8; ++j) {
                ahi[j] = (short)(uu[j] & 0xffffu);
                alo[j] = (short)(uu[j] >> 16);
            }
            const short8* wh = Wh + (size_t)(kc * 8) * 64 + lane;
            const short8* wl = Wl + (size_t)(kc * 8) * 64 + lane;
            #pragma unroll
            for (int n = 0; n < 8; ++n) {
                const short8 bh = wh[n * 64], bl = wl[n * 64];
                acc[n] = __builtin_amdgcn_mfma_f32_16x16x32_bf16(ahi, bh, acc[n], 0, 0, 0);
                acc[n] = __builtin_amdgcn_mfma_f32_16x16x32_bf16(ahi, bl, acc[n], 0, 0, 0);
                acc[n] = __builtin_amdgcn_mfma_f32_16x16x32_bf16(alo, bh, acc[n], 0, 0, 0);
            }
        }
        #pragma unroll
        for (int n = 0; n < 8; ++n) {
            const int col = n * 16 + l15;
            #pragma unroll
            for (int r = 0; r < 4; ++r) {
                const int node = tile * 16 + quad * 4 + r;
                if (node < N)
                    a.ru[(size_t)(b * N + node) * 128 + col] =
                        1.f / (1.f + __expf(-acc[n][r]));
            }
        }
    }
}

__device__ void cand_b(const MegaArgs& a, int l, int K3p, float* __restrict__ h,
                       bool doproj, float* __restrict__ outp, int b)
{
    const int wave = threadIdx.x >> 6, lane = threadIdx.x & 63;
    const int quad = lane >> 4, l15 = lane & 15;
    const short8* __restrict__ Wh = a.Wch[l];
    const short8* __restrict__ Wl = a.Wcl[l];
    const float*  __restrict__ bias = a.bc[l];
    const int KC = K3p >> 5;
    for (int tile = wave; tile < NTILE; tile += 16) {
        floatx4 acc[4];
        #pragma unroll
        for (int n = 0; n < 4; ++n) {
            const float bv = bias[n * 16 + l15];
            acc[n] = (floatx4){bv, bv, bv, bv};
        }
        int nodeA = tile * 16 + l15;
        if (nodeA > N - 1) nodeA = N - 1;
        const unsigned* __restrict__ zrow =
            a.zcat + (size_t)(b * N + nodeA) * K3p + quad * 8;
        for (int kc = 0; kc < KC; ++kc) {
            const uint4* p = (const uint4*)(zrow + kc * 32);
            const uint4 u0 = p[0], u1 = p[1];
            const unsigned uu[8] = {u0.x, u0.y, u0.z, u0.w, u1.x, u1.y, u1.z, u1.w};
            short8 ahi, alo;
            #pragma unroll
            for (int j = 0; j < 8; ++j) {
                ahi[j] = (short)(uu[j] & 0xffffu);
                alo[j] = (short)(uu[j] >> 16);
            }
            const short8* wh = Wh + (size_t)(kc * 4) * 64 + lane;
            const short8* wl = Wl + (size_t)(kc * 4) * 64 + lane;
            #pragma unroll
            for (int n = 0; n < 4; ++n) {
                const short8 bh = wh[n * 64], bl = wl[n * 64];
                acc[n] = __builtin_amdgcn_mfma_f32_16x16x32_bf16(ahi, bh, acc[n], 0, 0, 0);
                acc[n] = __builtin_amdgcn_mfma_f32_16x16x32_bf16(ahi, bl, acc[n], 0, 0, 0);
                acc[n] = __builtin_amdgcn_mfma_f32_16x16x32_bf16(alo, bh, acc[n], 0, 0, 0);
            }
        }
        float hn[4][4];
        #pragma unroll
        for (int n = 0; n < 4; ++n) {
            const int col = n * 16 + l15;
            #pragma unroll
            for (int r = 0; r < 4; ++r) {
                const int node = tile * 16 + quad * 4 + r;
                float nh = 0.f;
                if (node < N) {
                    const int row = b * N + node;
                    const float c  = tanhf(acc[n][r]);
                    const float ug = a.ru[(size_t)row * 128 + 64 + col];
                    const float hv = h[(size_t)row * 64 + col];
                    nh = ug * hv + (1.f - ug) * c;
                    h[(size_t)row * 64 + col] = nh;
                }
                hn[n][r] = nh;
            }
        }
        if (doproj) {
            float partial[4] = {0.f, 0.f, 0.f, 0.f};
            #pragma unroll
            for (int n = 0; n < 4; ++n) {
                const float w = a.pW[n * 16 + l15];
                #pragma unroll
                for (int r = 0; r < 4; ++r) partial[r] += hn[n][r] * w;
            }
            #pragma unroll
            for (int r = 0; r < 4; ++r) {
                float v = partial[r];
                v += __shfl_xor(v, 1, 16);
                v += __shfl_xor(v, 2, 16);
                v += __shfl_xor(v, 4, 16);
                v += __shfl_xor(v, 8, 16);
                const int node = tile * 16 + quad * 4 + r;
                if (l15 == 0 && node < N) {
                    const int row = b * N + node;
                    const float o = v + a.pb[0];
                    outp[row]     = o;
                    a.dec_in[row] = o;
                }
            }
        }
    }
}

// ---------------- split wrappers: 2 kernels per cell, per-sample blocks ----------------

__global__ __launch_bounds__(MBLK)
void dg_kernel(MegaArgs a, const float* __restrict__ x, int din, int F, int K3p,
               int l, float* __restrict__ h)
{
    __shared__ __align__(16) float s0[N * FC];
    __shared__ __align__(16) float s1[N * FC];
    const int b = blockIdx.x;
    diff_b(a, false, x, h, din, F, K3p, s0, s1, b);   // ends with __syncthreads
    gate_b(a, l, K3p, b);
}

__global__ __launch_bounds__(MBLK)
void dc_kernel(MegaArgs a, const float* __restrict__ x, int din, int F, int K3p,
               int l, float* __restrict__ h, int doproj, float* __restrict__ outp)
{
    __shared__ __align__(16) float s0[N * FC];
    __shared__ __align__(16) float s1[N * FC];
    const int b = blockIdx.x;
    diff_b(a, true, x, h, din, F, K3p, s0, s1, b);    // ends with __syncthreads
    cand_b(a, l, K3p, h, doproj != 0, outp, b);
}

// ---------------- host launcher ----------------

extern "C" void kernel_launch(void* const* d_in, const int* in_sizes, int n_in,
                              void* d_out, int out_size, void* d_ws, size_t ws_size,
                              hipStream_t stream)
{
    MegaArgs a;
    a.inputs = (const float*)d_in[0];
    a.S      = (const float*)d_in[1];
    for (int l = 0; l < 4; ++l) {
        a.Wg[l] = (const float*)d_in[2 + l * 4 + 0];
        a.bg[l] = (const float*)d_in[2 + l * 4 + 1];
        a.Wc[l] = (const float*)d_in[2 + l * 4 + 2];
        a.bc[l] = (const float*)d_in[2 + l * 4 + 3];
    }
    a.pW  = (const float*)d_in[18];
    a.pb  = (const float*)d_in[19];
    a.out = (float*)d_out;

    float* ws = (float*)d_ws;
    a.h0     = ws;
    a.h1     = a.h0 + BN * U;
    a.dec_in = a.h1 + BN * U;
    a.ru     = a.dec_in + BN;
    a.zcat   = (unsigned*)(a.ru + BN * 128);
    a.ellcv  = (float2*)(a.zcat + (size_t)BN * 384);
    a.nnz    = (int*)(a.ellcv + (size_t)ELLW * N);
    char* wp = (char*)(a.nnz + ((N + 3) & ~3));
    wp = (char*)(((uintptr_t)wp + 63) & ~(uintptr_t)63);

    const int K3ps[4] = {224, 384, 224, 384};
    size_t off = 0;
    for (int l = 0; l < 4; ++l) {
        const size_t ge = (size_t)K3ps[l] * 128, ce = (size_t)K3ps[l] * 64;
        a.Wgh[l] = (short8*)(wp + off); off += ge * 2;
        a.Wgl[l] = (short8*)(wp + off); off += ge * 2;
        a.Wch[l] = (short8*)(wp + off); off += ce * 2;
        a.Wcl[l] = (short8*)(wp + off); off += ce * 2;
    }

    setup_kernel<<<SGRID, 256, 0, stream>>>(a);

    auto cell = [&](const float* x, int din, int F, int K3p, float* h, int l,
                    int proj, float* outp) {
        dg_kernel<<<B, MBLK, 0, stream>>>(a, x, din, F, K3p, l, h);
        dc_kernel<<<B, MBLK, 0, stream>>>(a, x, din, F, K3p, l, h, proj, outp);
    };

    for (int t = 0; t < T; ++t) {
        cell(a.inputs + (size_t)t * BN * 2, 2, 66, 224, a.h0, 0, 0, nullptr);
        cell(a.h0, 64, 128, 384, a.h1, 1, 0, nullptr);
    }
    for (int s = 0; s < HZ; ++s) {
        cell(a.dec_in, 1, 65, 224, a.h0, 2, 0, nullptr);
        cell(a.h0, 64, 128, 384, a.h1, 3, 1, a.out + (size_t)s * BN);
    }
}